// Round 1
// baseline (453.258 us; speedup 1.0000x reference)
//
#include <hip/hip_runtime.h>

// VectorQuantizer on MI355X — round 0: correct fp32 baseline.
// latent [32,256,32,32] fp32, codebook [1024,256] fp32.
// out = [ q_st (8,388,608 fp32) | loss (1 fp32) ].
// ws  = [ idx (32768 int) | e2 (1024 fp32) ].

#define B_   32
#define D_   256
#define HW_  1024
#define N_   32768
#define K_   1024

// ---------- numpy-pairwise fp32 sum-of-squares per codebook row ----------
// Replicates np.sum(cb*cb, axis=1) rounding: square rounded, 8-accumulator
// base case over each 128-half, halves combined last. No FMA contraction.
__global__ __launch_bounds__(256) void k_e2(const float* __restrict__ cb,
                                            float* __restrict__ e2) {
  int g = blockIdx.x * 256 + threadIdx.x;   // 0..1023 rows
  const float* row = cb + g * 256;
  float h[2];
#pragma unroll
  for (int hh = 0; hh < 2; ++hh) {
    const float* p = row + hh * 128;
    float r[8];
#pragma unroll
    for (int j = 0; j < 8; ++j) r[j] = __fmul_rn(p[j], p[j]);
    for (int i = 8; i < 128; i += 8)
#pragma unroll
      for (int j = 0; j < 8; ++j)
        r[j] = __fadd_rn(r[j], __fmul_rn(p[i + j], p[i + j]));
    h[hh] = __fadd_rn(__fadd_rn(__fadd_rn(r[0], r[1]), __fadd_rn(r[2], r[3])),
                      __fadd_rn(__fadd_rn(r[4], r[5]), __fadd_rn(r[6], r[7])));
  }
  e2[g] = __fadd_rn(h[0], h[1]);
}

// ---------- fused distance-GEMM + argmin ----------
// Block: 64 positions (one hw-contiguous strip within a batch) vs all 1024
// codes in k-tiles of 128. D staged in chunks of 16 via LDS. Micro-tile
// 4n x 8k per thread (256 thr = 16 nth x 16 kth). Score replicates np:
// round(round(x2 + e2k) - 2*dot), first-min tie-break (k ascending).
__global__ __launch_bounds__(256, 4) void k_argmin(
    const float* __restrict__ latent, const float* __restrict__ cb,
    const float* __restrict__ e2g, int* __restrict__ idxg) {
  __shared__ float Xs[16 * 64];        // [dd][n]   4 KB
  __shared__ float Es[128 * 20];       // [kk][dd] (16 padded to 20) 10 KB
  __shared__ float x2s[64];
  __shared__ float halves[2][64];

  const int t   = threadIdx.x;
  const int blk = blockIdx.x;          // 512 blocks
  const int b   = blk >> 4;
  const int hw0 = (blk & 15) * 64;
  const float* Xbase = latent + (size_t)b * (D_ * HW_) + hw0;

  // x2 per position, numpy pairwise order (two halves of 128, 8 accums)
  if (t < 128) {
    int p = t & 63, hh = t >> 6;
    const float* base = Xbase + (hh * 128) * HW_ + p;
    float r[8];
#pragma unroll
    for (int j = 0; j < 8; ++j) {
      float v = base[j * HW_];
      r[j] = __fmul_rn(v, v);
    }
    for (int i = 8; i < 128; i += 8)
#pragma unroll
      for (int j = 0; j < 8; ++j) {
        float v = base[(i + j) * HW_];
        r[j] = __fadd_rn(r[j], __fmul_rn(v, v));
      }
    halves[hh][p] =
        __fadd_rn(__fadd_rn(__fadd_rn(r[0], r[1]), __fadd_rn(r[2], r[3])),
                  __fadd_rn(__fadd_rn(r[4], r[5]), __fadd_rn(r[6], r[7])));
  }
  __syncthreads();
  if (t < 64) x2s[t] = __fadd_rn(halves[0][t], halves[1][t]);
  // (first __syncthreads of the dc loop orders x2s before any epilogue read)

  const int kth = t & 15;              // code lane within tile
  const int nth = t >> 4;              // position group (4 n each)

  float best[4];
  int bestk[4];
#pragma unroll
  for (int i = 0; i < 4; ++i) { best[i] = 3.4e38f; bestk[i] = 0; }

  for (int kt = 0; kt < 8; ++kt) {
    const int k0 = kt * 128;
    float acc[4][8];
#pragma unroll
    for (int i = 0; i < 4; ++i)
#pragma unroll
      for (int j = 0; j < 8; ++j) acc[i][j] = 0.f;

    for (int dc = 0; dc < 16; ++dc) {
      const int d0 = dc * 16;
      __syncthreads();
      { // stage X tile: 256 float4, fully coalesced
        int dd = t >> 4, iq = t & 15;
        *(float4*)(Xs + dd * 64 + iq * 4) =
            *(const float4*)(Xbase + (size_t)(d0 + dd) * HW_ + iq * 4);
      }
#pragma unroll
      for (int e = 0; e < 2; ++e) { // stage E tile: 512 float4
        int id = t + 256 * e;
        int kk = id >> 2, q = id & 3;
        *(float4*)(Es + kk * 20 + q * 4) =
            *(const float4*)(cb + (size_t)(k0 + kk) * 256 + d0 + q * 4);
      }
      __syncthreads();
#pragma unroll
      for (int dq = 0; dq < 4; ++dq) {
        float xa[4][4] __attribute__((aligned(16)));  // [id(d)][i(n)]
#pragma unroll
        for (int id = 0; id < 4; ++id)
          *(float4*)xa[id] =
              *(const float4*)(Xs + (dq * 4 + id) * 64 + nth * 4);
        float eb[8][4] __attribute__((aligned(16)));  // [j(k)][id(d)]
#pragma unroll
        for (int j = 0; j < 8; ++j)
          *(float4*)eb[j] =
              *(const float4*)(Es + (kth + 16 * j) * 20 + dq * 4);
#pragma unroll
        for (int j = 0; j < 8; ++j)
#pragma unroll
          for (int id = 0; id < 4; ++id) {
            float e = eb[j][id];
#pragma unroll
            for (int i = 0; i < 4; ++i)
              acc[i][j] = fmaf(xa[id][i], e, acc[i][j]);
          }
      }
    }
    // epilogue: scores for this k-tile, strict < keeps first (smallest k)
#pragma unroll
    for (int j = 0; j < 8; ++j) {
      int k = k0 + kth + 16 * j;
      float e2k = e2g[k];
#pragma unroll
      for (int i = 0; i < 4; ++i) {
        float t1 = __fadd_rn(x2s[nth * 4 + i], e2k);   // round(A+B)
        float s  = __fadd_rn(t1, -2.f * acc[i][j]);    // round(. - 2C)
        if (s < best[i]) { best[i] = s; bestk[i] = k; }
      }
    }
  }
  // reduce across the 16 kth lanes (same wave); ties -> smaller k
#pragma unroll
  for (int m = 1; m < 16; m <<= 1) {
#pragma unroll
    for (int i = 0; i < 4; ++i) {
      float ob = __shfl_xor(best[i], m, 64);
      int   ok = __shfl_xor(bestk[i], m, 64);
      if (ob < best[i] || (ob == best[i] && ok < bestk[i])) {
        best[i] = ob; bestk[i] = ok;
      }
    }
  }
  if (kth == 0) {
#pragma unroll
    for (int i = 0; i < 4; ++i) idxg[blk * 64 + nth * 4 + i] = bestk[i];
  }
}

// ---------- gather + straight-through output + loss ----------
// Block: 32 positions. Gathered codes staged row-contiguous from L2, written
// transposed into padded LDS (stride 33: conflict-free read at fixed d).
// out = x + (q - x) in fp32 (replicates jnp q_st rounding exactly).
__global__ __launch_bounds__(256, 2) void k_out(
    const float* __restrict__ latent, const float* __restrict__ cb,
    const int* __restrict__ idxg, float* __restrict__ out,
    float* __restrict__ loss) {
  __shared__ float q_lds[256 * 33];   // [d][p], pad 32->33
  __shared__ int idxs[32];
  __shared__ float red[256];
  const int t = threadIdx.x, blk = blockIdx.x;   // 1024 blocks
  const int b = blk >> 5, hw0 = (blk & 31) * 32;
  if (t < 32) idxs[t] = idxg[blk * 32 + t];
  __syncthreads();
  { // stage 32 selected rows (8 float4 per thread, row-contiguous loads)
    int r = t >> 3;
    int c0 = (t & 7) * 8;
    const float4* src = (const float4*)(cb + (size_t)idxs[r] * 256);
#pragma unroll
    for (int c = 0; c < 8; ++c) {
      float4 v = src[c0 + c];
      int d = (c0 + c) * 4;
      q_lds[(d + 0) * 33 + r] = v.x;
      q_lds[(d + 1) * 33 + r] = v.y;
      q_lds[(d + 2) * 33 + r] = v.z;
      q_lds[(d + 3) * 33 + r] = v.w;
    }
  }
  __syncthreads();
  const int p = t & 31, dg = t >> 5;   // 8 d-groups x 32 iters
  const float* Xb = latent + (size_t)b * (D_ * HW_) + hw0 + p;
  float* Ob = out + (size_t)b * (D_ * HW_) + hw0 + p;
  float part = 0.f;
#pragma unroll 4
  for (int it = 0; it < 32; ++it) {
    int d = dg * 32 + it;
    float q = q_lds[d * 33 + p];
    float x = Xb[(size_t)d * HW_];
    float dd = __fsub_rn(q, x);
    Ob[(size_t)d * HW_] = __fadd_rn(x, dd);   // x + (q - x), NOT q
    part = fmaf(dd, dd, part);
  }
  red[t] = part;
  __syncthreads();
  for (int s = 128; s > 0; s >>= 1) {
    if (t < s) red[t] += red[t + s];
    __syncthreads();
  }
  if (t == 0) atomicAdd(loss, red[0] * (1.25f / 8388608.0f));
}

extern "C" void kernel_launch(void* const* d_in, const int* in_sizes, int n_in,
                              void* d_out, int out_size, void* d_ws, size_t ws_size,
                              hipStream_t stream) {
  const float* latent = (const float*)d_in[0];
  const float* cb     = (const float*)d_in[1];
  float* out  = (float*)d_out;
  float* loss = out + (size_t)N_ * D_;                    // element 8,388,608
  int*   idxg = (int*)d_ws;
  float* e2   = (float*)((char*)d_ws + (size_t)N_ * sizeof(int));

  hipMemsetAsync(loss, 0, sizeof(float), stream);         // ws/out are poisoned
  hipLaunchKernelGGL(k_e2,     dim3(4),    dim3(256), 0, stream, cb, e2);
  hipLaunchKernelGGL(k_argmin, dim3(512),  dim3(256), 0, stream, latent, cb, e2, idxg);
  hipLaunchKernelGGL(k_out,    dim3(1024), dim3(256), 0, stream, latent, cb, idxg, out, loss);
}

// Round 2
// 194.517 us; speedup vs baseline: 2.3302x; 2.3302x over previous
//
#include <hip/hip_runtime.h>

// VectorQuantizer on MI355X — round 1: split-bf16 MFMA distance GEMM.
// latent [32,256,1024] fp32, codebook [1024,256] fp32.
// out = [ q_st (8,388,608 fp32) | loss (1 fp32) ]; Ehi/Elo bf16 scratch parked
// at out+16MB (consumed by k_argmin, overwritten by k_out afterwards).
// ws = [ packed u64[32768] | x2 f32[32768] | e2 f32[1024] ]  (~388 KB).

#define D_   256
#define HW_  1024
#define N_   32768
#define K_   1024

typedef __attribute__((ext_vector_type(8))) short  s8v;   // 8 bf16 (4 VGPR)
typedef __attribute__((ext_vector_type(4))) float  f4v;   // MFMA acc

// truncating split: x ~= hi + lo (each bf16 bits), |err| <= 2^-16 |x|
__device__ inline void split2(float x, ushort& hi, ushort& lo) {
  unsigned xb = __float_as_uint(x);
  hi = (ushort)(xb >> 16);
  float hif = __uint_as_float(xb & 0xFFFF0000u);
  float lof = __fsub_rn(x, hif);                  // exact
  lo = (ushort)(__float_as_uint(lof) >> 16);
}

// ---------- numpy-pairwise fp32 sum-of-squares per codebook row ----------
__global__ __launch_bounds__(256) void k_e2(const float* __restrict__ cb,
                                            float* __restrict__ e2) {
  int g = blockIdx.x * 256 + threadIdx.x;   // 0..1023 rows
  const float* row = cb + g * 256;
  float h[2];
#pragma unroll
  for (int hh = 0; hh < 2; ++hh) {
    const float* p = row + hh * 128;
    float r[8];
#pragma unroll
    for (int j = 0; j < 8; ++j) r[j] = __fmul_rn(p[j], p[j]);
    for (int i = 8; i < 128; i += 8)
#pragma unroll
      for (int j = 0; j < 8; ++j)
        r[j] = __fadd_rn(r[j], __fmul_rn(p[i + j], p[i + j]));
    h[hh] = __fadd_rn(__fadd_rn(__fadd_rn(r[0], r[1]), __fadd_rn(r[2], r[3])),
                      __fadd_rn(__fadd_rn(r[4], r[5]), __fadd_rn(r[6], r[7])));
  }
  e2[g] = __fadd_rn(h[0], h[1]);
}

// ---------- numpy-pairwise x2 per position ----------
__global__ __launch_bounds__(256) void k_x2(const float* __restrict__ latent,
                                            float* __restrict__ x2g) {
  __shared__ float halves[2][128];
  const int t = threadIdx.x, blk = blockIdx.x;   // 256 blocks x (128 pos, 2 halves)
  const int pl = t & 127, hh = t >> 7;
  const int p = blk * 128 + pl;
  const int b = p >> 10, hw = p & 1023;
  const float* base = latent + (size_t)b * (D_ * HW_) + (size_t)(hh * 128) * HW_ + hw;
  float r[8];
#pragma unroll
  for (int j = 0; j < 8; ++j) {
    float v = base[j * HW_];
    r[j] = __fmul_rn(v, v);
  }
  for (int i = 8; i < 128; i += 8)
#pragma unroll
    for (int j = 0; j < 8; ++j) {
      float v = base[(i + j) * HW_];
      r[j] = __fadd_rn(r[j], __fmul_rn(v, v));
    }
  halves[hh][pl] =
      __fadd_rn(__fadd_rn(__fadd_rn(r[0], r[1]), __fadd_rn(r[2], r[3])),
                __fadd_rn(__fadd_rn(r[4], r[5]), __fadd_rn(r[6], r[7])));
  __syncthreads();
  if (t < 128) x2g[blk * 128 + t] = __fadd_rn(halves[0][t], halves[1][t]);
}

// ---------- codebook -> bf16 hi/lo split ----------
__global__ __launch_bounds__(256) void k_convE(const float* __restrict__ cb,
                                               ushort* __restrict__ Ehi_g,
                                               ushort* __restrict__ Elo_g) {
  int gid = blockIdx.x * 256 + threadIdx.x;   // 65536 threads x 4 elems
  int code = gid >> 6, dq = gid & 63;
  float4 v = *(const float4*)(cb + (size_t)code * 256 + dq * 4);
  ushort4 h, l;
  split2(v.x, h.x, l.x); split2(v.y, h.y, l.y);
  split2(v.z, h.z, l.z); split2(v.w, h.w, l.w);
  *(ushort4*)(Ehi_g + (size_t)code * 256 + dq * 4) = h;
  *(ushort4*)(Elo_g + (size_t)code * 256 + dq * 4) = l;
}

// ---------- fused split-bf16 MFMA distance GEMM + argmin ----------
// Grid 512 = 256 pos-tiles (128 pos) x 2 code-splits (512 codes).
// Block 512 thr = 8 waves: (wm 0..1) x (wk 0..3); wave tile 64 pos x 128 codes
// = 4m x 8k MFMA-tiles (16x16x32), acc 32 frags. D in 8 chunks of 32.
// Score = fadd(fadd(x2+e2), -2*dot) — same quantization as numpy.
// Result merged across waves/blocks via atomicMin on {score_bits:32 | k:32}.
__global__ __launch_bounds__(512, 2) void k_argmin(
    const float* __restrict__ latent, const ushort* __restrict__ Ehi_g,
    const ushort* __restrict__ Elo_g, const float* __restrict__ e2g,
    const float* __restrict__ x2g, unsigned long long* __restrict__ packed) {
  __shared__ alignas(16) ushort Xhi[128 * 40], Xlo[128 * 40];   // pitch 40 u16
  __shared__ alignas(16) ushort Ehi[512 * 40], Elo[512 * 40];
  __shared__ float x2s[128];
  __shared__ float e2s[512];

  const int t = threadIdx.x;
  const int bid = blockIdx.x;
  const int split = bid & 1;
  const int tile  = bid >> 1;            // 0..255
  const int bX  = tile >> 3;
  const int hw0 = (tile & 7) * 128;
  const int k_base = split * 512;

  if (t < 128) x2s[t] = x2g[tile * 128 + t];
  e2s[t] = e2g[k_base + t];              // 512 threads, 512 codes

  f4v acc[4][8];
#pragma unroll
  for (int mi = 0; mi < 4; ++mi)
#pragma unroll
    for (int kj = 0; kj < 8; ++kj) acc[mi][kj] = (f4v){0.f, 0.f, 0.f, 0.f};

  const int lane = t & 63;
  const int w = t >> 6;
  const int wm = w >> 2, wk = w & 3;
  const int lrow = lane & 15, q = lane >> 4;

  for (int ch = 0; ch < 8; ++ch) {
    const int d0 = ch * 32;
    __syncthreads();
    // --- stage X chunk (convert fp32 -> hi/lo), lane == position => 2-way free
    {
#pragma unroll
      for (int rr = 0; rr < 8; ++rr) {
        int id = t + rr * 512;            // 4096 = 128 pos x 32 d
        int p = id & 127, dd = id >> 7;
        float v = latent[(size_t)bX * (D_ * HW_) + (size_t)(d0 + dd) * HW_ + hw0 + p];
        ushort hi, lo;
        split2(v, hi, lo);
        Xhi[p * 40 + dd] = hi;
        Xlo[p * 40 + dd] = lo;
      }
    }
    // --- stage E chunk (pure bf16 copy from L2)
    {
#pragma unroll
      for (int rr = 0; rr < 4; ++rr) {
        int id = t + rr * 512;            // 2048 = 512 codes x 4 parts
        int code = id >> 2, part = id & 3;
        *(uint4*)&Ehi[code * 40 + part * 8] =
            *(const uint4*)(Ehi_g + (size_t)(k_base + code) * 256 + d0 + part * 8);
        *(uint4*)&Elo[code * 40 + part * 8] =
            *(const uint4*)(Elo_g + (size_t)(k_base + code) * 256 + d0 + part * 8);
      }
    }
    __syncthreads();

    s8v ah[4], al[4];
#pragma unroll
    for (int mi = 0; mi < 4; ++mi) {
      int row = wm * 64 + mi * 16 + lrow;
      ah[mi] = *(const s8v*)&Xhi[row * 40 + q * 8];
      al[mi] = *(const s8v*)&Xlo[row * 40 + q * 8];
    }
#pragma unroll
    for (int kj = 0; kj < 8; ++kj) {
      int row = wk * 128 + kj * 16 + lrow;
      s8v bh = *(const s8v*)&Ehi[row * 40 + q * 8];
      s8v bl = *(const s8v*)&Elo[row * 40 + q * 8];
#pragma unroll
      for (int mi = 0; mi < 4; ++mi) {
        acc[mi][kj] = __builtin_amdgcn_mfma_f32_16x16x32_bf16(al[mi], bh, acc[mi][kj], 0, 0, 0);
        acc[mi][kj] = __builtin_amdgcn_mfma_f32_16x16x32_bf16(ah[mi], bl, acc[mi][kj], 0, 0, 0);
        acc[mi][kj] = __builtin_amdgcn_mfma_f32_16x16x32_bf16(ah[mi], bh, acc[mi][kj], 0, 0, 0);
      }
    }
  }

  // --- epilogue: numpy-quantized scores, per-lane argmin, butterfly, atomic
  float e2v[8];
#pragma unroll
  for (int kj = 0; kj < 8; ++kj) e2v[kj] = e2s[wk * 128 + kj * 16 + lrow];
#pragma unroll
  for (int mi = 0; mi < 4; ++mi) {
#pragma unroll
    for (int reg = 0; reg < 4; ++reg) {
      float xv = x2s[wm * 64 + mi * 16 + q * 4 + reg];
      float best = 3.4e38f;
      int bk = 0;
#pragma unroll
      for (int kj = 0; kj < 8; ++kj) {   // kj ascending => first-min tie-break
        float s = __fadd_rn(__fadd_rn(xv, e2v[kj]), -2.f * acc[mi][kj][reg]);
        if (s < best) { best = s; bk = k_base + wk * 128 + kj * 16 + lrow; }
      }
#pragma unroll
      for (int m = 1; m < 16; m <<= 1) {
        float ob = __shfl_xor(best, m, 64);
        int   ok = __shfl_xor(bk, m, 64);
        if (ob < best || (ob == best && ok < bk)) { best = ob; bk = ok; }
      }
      if (lrow == 0) {
        int p = tile * 128 + wm * 64 + mi * 16 + q * 4 + reg;
        unsigned long long pk =
            ((unsigned long long)__float_as_uint(best) << 32) | (unsigned)bk;
        atomicMin(&packed[p], pk);
      }
    }
  }
}

// ---------- gather + straight-through output + loss ----------
__global__ __launch_bounds__(256, 4) void k_out(
    const float* __restrict__ latent, const float* __restrict__ cb,
    const unsigned long long* __restrict__ packed, float* __restrict__ out,
    float* __restrict__ loss) {
  __shared__ float q_lds[256 * 33];   // [d][p], pad 32->33
  __shared__ int idxs[32];
  __shared__ float red[4];
  const int t = threadIdx.x, blk = blockIdx.x;   // 1024 blocks x 32 pos
  const int b = blk >> 5, hw0 = (blk & 31) * 32;
  if (t < 32) idxs[t] = (int)(unsigned)(packed[blk * 32 + t] & 0xFFFFFFFFull);
  __syncthreads();
  { // stage 32 selected rows, transposed into LDS
    int r = t >> 3;
    int c0 = (t & 7) * 8;
    const float4* src = (const float4*)(cb + (size_t)idxs[r] * 256);
#pragma unroll
    for (int c = 0; c < 8; ++c) {
      float4 v = src[c0 + c];
      int d = (c0 + c) * 4;
      q_lds[(d + 0) * 33 + r] = v.x;
      q_lds[(d + 1) * 33 + r] = v.y;
      q_lds[(d + 2) * 33 + r] = v.z;
      q_lds[(d + 3) * 33 + r] = v.w;
    }
  }
  __syncthreads();
  const int p = t & 31, dg = t >> 5;
  const float* Xb = latent + (size_t)b * (D_ * HW_) + hw0 + p;
  float* Ob = out + (size_t)b * (D_ * HW_) + hw0 + p;
  float part = 0.f;
#pragma unroll 4
  for (int it = 0; it < 32; ++it) {
    int d = dg * 32 + it;
    float qv = q_lds[d * 33 + p];
    float x  = Xb[(size_t)d * HW_];
    float dd = __fsub_rn(qv, x);
    Ob[(size_t)d * HW_] = __fadd_rn(x, dd);   // x + (q - x), NOT q
    part = fmaf(dd, dd, part);
  }
#pragma unroll
  for (int off = 32; off > 0; off >>= 1) part += __shfl_down(part, off, 64);
  if ((t & 63) == 0) red[t >> 6] = part;
  __syncthreads();
  if (t == 0)
    atomicAdd(loss, (red[0] + red[1] + red[2] + red[3]) * (1.25f / 8388608.0f));
}

extern "C" void kernel_launch(void* const* d_in, const int* in_sizes, int n_in,
                              void* d_out, int out_size, void* d_ws, size_t ws_size,
                              hipStream_t stream) {
  const float* latent = (const float*)d_in[0];
  const float* cb     = (const float*)d_in[1];
  float* out  = (float*)d_out;
  float* loss = out + (size_t)N_ * D_;                 // element 8,388,608
  // bf16 split codebook parked in d_out (byte offset 16 MB; k_out overwrites later)
  ushort* Ehi_g = (ushort*)(out + 4194304);
  ushort* Elo_g = Ehi_g + K_ * D_;
  unsigned long long* packed = (unsigned long long*)d_ws;
  float* x2g = (float*)((char*)d_ws + (size_t)N_ * 8);
  float* e2  = x2g + N_;

  hipMemsetAsync(packed, 0xFF, (size_t)N_ * 8, stream);  // max-u64 init
  hipMemsetAsync(loss, 0, sizeof(float), stream);
  hipLaunchKernelGGL(k_convE,  dim3(256),  dim3(256), 0, stream, cb, Ehi_g, Elo_g);
  hipLaunchKernelGGL(k_e2,     dim3(4),    dim3(256), 0, stream, cb, e2);
  hipLaunchKernelGGL(k_x2,     dim3(256),  dim3(256), 0, stream, latent, x2g);
  hipLaunchKernelGGL(k_argmin, dim3(512),  dim3(512), 0, stream, latent, Ehi_g, Elo_g, e2, x2g, packed);
  hipLaunchKernelGGL(k_out,    dim3(1024), dim3(256), 0, stream, latent, cb, packed, out, loss);
}

// Round 3
// 146.493 us; speedup vs baseline: 3.0941x; 1.3278x over previous
//
#include <hip/hip_runtime.h>
#include <stdint.h>

// VectorQuantizer on MI355X — round 2: single-bf16 MFMA + DMA staging.
// latent [32,256,1024] fp32, codebook [1024,256] fp32.
// d_out float regions: Xt bf16 [0,4194304) | Ebf bf16 @4718592 | x2 @4849664
// | e2 @4882432 — all consumed by k_argmin, then overwritten by k_out's q_st.
// ws = packed u64[32768] (atomicMin of {score_bits:32|k:32}).

#define D_   256
#define HW_  1024
#define N_   32768
#define K_   1024

typedef __attribute__((ext_vector_type(8))) short  s8v;   // 8 bf16 (4 VGPR)
typedef __attribute__((ext_vector_type(4))) float  f4v;   // MFMA acc

__device__ __forceinline__ ushort bf16rne(float x) {
  unsigned u = __float_as_uint(x);
  return (ushort)((u + 0x7FFFu + ((u >> 16) & 1u)) >> 16);
}

// async global->LDS DMA, 16 B/lane; LDS dest = wave-uniform base + lane*16
__device__ __forceinline__ void gld_lds16(const void* g, void* l) {
  __builtin_amdgcn_global_load_lds(
      (const __attribute__((address_space(1))) unsigned int*)g,
      (__attribute__((address_space(3))) unsigned int*)l, 16, 0, 0);
}

// ---------- codebook -> bf16 (RNE) + numpy-pairwise e2 ----------
__global__ __launch_bounds__(256) void k_eprep(const float* __restrict__ cb,
                                               ushort* __restrict__ Ebf,
                                               float* __restrict__ e2) {
  const int t = threadIdx.x, blk = blockIdx.x;   // 64 blocks x 16 rows
#pragma unroll
  for (int i = 0; i < 4; ++i) {                  // convert 4096 floats
    int idx4 = blk * 1024 + i * 256 + t;
    float4 v = ((const float4*)cb)[idx4];
    ushort4 o;
    o.x = bf16rne(v.x); o.y = bf16rne(v.y);
    o.z = bf16rne(v.z); o.w = bf16rne(v.w);
    ((ushort4*)Ebf)[idx4] = o;
  }
  // e2: 16 lanes/row; lane(sub)= h*8+j accumulates r[j] of half h in numpy
  // order, then xor-butterfly reproduces numpy's pairwise tree at sub==0.
  const int row = blk * 16 + (t >> 4);
  const int sub = t & 15, j = sub & 7, h = sub >> 3;
  const float* base = cb + row * 256 + h * 128 + j;
  float r = __fmul_rn(base[0], base[0]);
  for (int i = 1; i < 16; ++i) {
    float v = base[8 * i];
    r = __fadd_rn(r, __fmul_rn(v, v));
  }
#pragma unroll
  for (int m = 1; m < 16; m <<= 1) r = __fadd_rn(r, __shfl_xor(r, m, 64));
  if (sub == 0) e2[row] = r;
}

// ---------- latent -> position-major bf16 (RNE) + numpy-pairwise x2 ----------
__global__ __launch_bounds__(256) void k_xprep(const float* __restrict__ latent,
                                               ushort* __restrict__ Xt,
                                               float* __restrict__ x2g) {
  __shared__ float Xf[32 * 257];                 // [p][d] pitch 257 (conflict-free)
  __shared__ float hv[2][32];
  const int t = threadIdx.x, tile = blockIdx.x;  // 1024 tiles x 32 positions
  const int b = tile >> 5, hw0 = (tile & 31) * 32;
  const float* Lb = latent + (size_t)b * (D_ * HW_) + hw0;
#pragma unroll
  for (int i = 0; i < 8; ++i) {                  // [256 d][32 hw] float4 in
    int idx = i * 256 + t;
    int d = idx >> 3, qq = idx & 7;
    float4 v = *(const float4*)(Lb + (size_t)d * HW_ + qq * 4);
    Xf[(qq * 4 + 0) * 257 + d] = v.x;
    Xf[(qq * 4 + 1) * 257 + d] = v.y;
    Xf[(qq * 4 + 2) * 257 + d] = v.z;
    Xf[(qq * 4 + 3) * 257 + d] = v.w;
  }
  __syncthreads();
#pragma unroll
  for (int i = 0; i < 4; ++i) {                  // bf16 rows out (coalesced)
    int idx = i * 256 + t;
    int p = idx >> 5, part = idx & 31;
    const float* src = &Xf[p * 257 + part * 8];
    ushort tmp[8] __attribute__((aligned(16)));
#pragma unroll
    for (int e = 0; e < 8; ++e) tmp[e] = bf16rne(src[e]);
    *(uint4*)(Xt + (size_t)(tile * 32 + p) * 256 + part * 8) = *(uint4*)tmp;
  }
  if (t < 64) {                                  // x2, exact numpy order
    int p = t & 31, h = t >> 5;
    const float* a = &Xf[p * 257 + h * 128];
    float r[8];
#pragma unroll
    for (int j = 0; j < 8; ++j) r[j] = __fmul_rn(a[j], a[j]);
    for (int i = 8; i < 128; i += 8)
#pragma unroll
      for (int j = 0; j < 8; ++j)
        r[j] = __fadd_rn(r[j], __fmul_rn(a[i + j], a[i + j]));
    hv[h][p] =
        __fadd_rn(__fadd_rn(__fadd_rn(r[0], r[1]), __fadd_rn(r[2], r[3])),
                  __fadd_rn(__fadd_rn(r[4], r[5]), __fadd_rn(r[6], r[7])));
  }
  __syncthreads();
  if (t < 32) x2g[tile * 32 + t] = __fadd_rn(hv[0][t], hv[1][t]);
}

// ---------- MFMA distance GEMM + argmin ----------
// Grid 1024 = 256 tiles (128 pos) x 4 code-splits (256 codes). Block 256 thr
// = 4 waves (wm x wk); wave tile 64 pos x 128 codes = 4m x 8k MFMA frags.
// BK=64 as two 32-d LDS planes so global_load_lds stays layout-contiguous
// and b128 frag reads stay bank-balanced. Score quantized like numpy:
// fadd(fadd(x2,e2), -2*dot); first-min tie-break; atomicMin merge.
__global__ __launch_bounds__(256, 2) void k_argmin(
    const ushort* __restrict__ Xt, const ushort* __restrict__ Ebf,
    const float* __restrict__ e2g, const float* __restrict__ x2g,
    unsigned long long* __restrict__ packed) {
  __shared__ alignas(16) ushort Xs[2][128 * 32];   // 16 KB
  __shared__ alignas(16) ushort Es[2][256 * 32];   // 32 KB
  __shared__ float x2s[128], e2s[256];
  const int t = threadIdx.x;
  const int split = blockIdx.x & 3, tile = blockIdx.x >> 2;
  const int k0 = split * 256;
  const int lane = t & 63, w = t >> 6;
  const int wm = w >> 1, wk = w & 1;
  const int lrow = lane & 15, q = lane >> 4;
  const int sp = lane >> 2, sd = lane & 3;

  if (t < 128) x2s[t] = x2g[tile * 128 + t];
  e2s[t] = e2g[k0 + t];

  f4v acc[4][8];
#pragma unroll
  for (int mi = 0; mi < 4; ++mi)
#pragma unroll
    for (int kj = 0; kj < 8; ++kj) acc[mi][kj] = (f4v){0.f, 0.f, 0.f, 0.f};

  const ushort* Xg = Xt + (size_t)tile * 128 * 256;
  const ushort* Eg = Ebf + (size_t)k0 * 256;

  for (int ch = 0; ch < 4; ++ch) {
    const int d0 = ch * 64;
    __syncthreads();                              // prev chunk consumed
#pragma unroll
    for (int s = 0; s < 2; ++s) {
      const int ds = d0 + s * 32;
#pragma unroll
      for (int ii = 0; ii < 2; ++ii) {            // X: 8 KB/plane, 2 insts/wave
        int xi = w * 2 + ii;
        gld_lds16(Xg + (size_t)(xi * 16 + sp) * 256 + ds + sd * 8,
                  &Xs[s][xi * 512 + lane * 8]);
      }
#pragma unroll
      for (int ii = 0; ii < 4; ++ii) {            // E: 16 KB/plane, 4 insts/wave
        int ei = w * 4 + ii;
        gld_lds16(Eg + (size_t)(ei * 16 + sp) * 256 + ds + sd * 8,
                  &Es[s][ei * 512 + lane * 8]);
      }
    }
    __syncthreads();                              // drains vmcnt (DMA done)
#pragma unroll
    for (int s = 0; s < 2; ++s) {
      s8v a_[4];
#pragma unroll
      for (int mi = 0; mi < 4; ++mi)
        a_[mi] = *(const s8v*)&Xs[s][(wm * 64 + mi * 16 + lrow) * 32 + q * 8];
#pragma unroll
      for (int kj = 0; kj < 8; ++kj) {
        s8v b_ = *(const s8v*)&Es[s][(wk * 128 + kj * 16 + lrow) * 32 + q * 8];
#pragma unroll
        for (int mi = 0; mi < 4; ++mi)
          acc[mi][kj] = __builtin_amdgcn_mfma_f32_16x16x32_bf16(
              a_[mi], b_, acc[mi][kj], 0, 0, 0);
      }
    }
  }

  float e2v[8];
#pragma unroll
  for (int kj = 0; kj < 8; ++kj) e2v[kj] = e2s[wk * 128 + kj * 16 + lrow];
#pragma unroll
  for (int mi = 0; mi < 4; ++mi) {
#pragma unroll
    for (int reg = 0; reg < 4; ++reg) {
      float xv = x2s[wm * 64 + mi * 16 + q * 4 + reg];
      float best = 3.4e38f;
      int bk = 0;
#pragma unroll
      for (int kj = 0; kj < 8; ++kj) {            // kj ascending: first-min
        float s = __fadd_rn(__fadd_rn(xv, e2v[kj]), -2.f * acc[mi][kj][reg]);
        if (s < best) { best = s; bk = k0 + wk * 128 + kj * 16 + lrow; }
      }
#pragma unroll
      for (int m = 1; m < 16; m <<= 1) {
        float ob = __shfl_xor(best, m, 64);
        int ok = __shfl_xor(bk, m, 64);
        if (ob < best || (ob == best && ok < bk)) { best = ob; bk = ok; }
      }
      if (lrow == 0) {
        int p = tile * 128 + wm * 64 + mi * 16 + q * 4 + reg;
        atomicMin(&packed[p],
                  ((unsigned long long)__float_as_uint(best) << 32) | (unsigned)bk);
      }
    }
  }
}

// ---------- gather + straight-through output + loss ----------
// Thread owns (pos-quad, 32-d group): 4 codebook 64B lines reused over 16
// consecutive d (L1-resident), x/out as contiguous float4 over hw.
__global__ __launch_bounds__(256, 4) void k_out(
    const float* __restrict__ latent, const float* __restrict__ cb,
    const unsigned long long* __restrict__ packed, float* __restrict__ out,
    float* __restrict__ loss) {
  __shared__ float red[4];
  const int gid = blockIdx.x * 256 + threadIdx.x;  // 65536
  const int pq = gid & 8191, dg = gid >> 13;
  const int b = pq >> 8, hwq = pq & 255;
  const size_t pbase = (size_t)b * 1024 + hwq * 4;
  int idx[4];
#pragma unroll
  for (int e = 0; e < 4; ++e)
    idx[e] = (int)(unsigned)(packed[pbase + e] & 0xFFFFFFFFull);
  const float* Lb = latent + (size_t)b * (D_ * HW_) + hwq * 4;
  float* Ob = out + (size_t)b * (D_ * HW_) + hwq * 4;
  float part = 0.f;
#pragma unroll 4
  for (int dd = 0; dd < 32; ++dd) {
    int d = dg * 32 + dd;
    float4 x = *(const float4*)(Lb + (size_t)d * HW_);
    float4 o;
    float qv, df;
    qv = cb[(size_t)idx[0] * 256 + d]; df = __fsub_rn(qv, x.x); o.x = __fadd_rn(x.x, df); part = fmaf(df, df, part);
    qv = cb[(size_t)idx[1] * 256 + d]; df = __fsub_rn(qv, x.y); o.y = __fadd_rn(x.y, df); part = fmaf(df, df, part);
    qv = cb[(size_t)idx[2] * 256 + d]; df = __fsub_rn(qv, x.z); o.z = __fadd_rn(x.z, df); part = fmaf(df, df, part);
    qv = cb[(size_t)idx[3] * 256 + d]; df = __fsub_rn(qv, x.w); o.w = __fadd_rn(x.w, df); part = fmaf(df, df, part);
    *(float4*)(Ob + (size_t)d * HW_) = o;      // x + (q - x), NOT q
  }
#pragma unroll
  for (int off = 32; off > 0; off >>= 1) part += __shfl_down(part, off, 64);
  if ((threadIdx.x & 63) == 0) red[threadIdx.x >> 6] = part;
  __syncthreads();
  if (threadIdx.x == 0)
    atomicAdd(loss, (red[0] + red[1] + red[2] + red[3]) * (1.25f / 8388608.0f));
}

extern "C" void kernel_launch(void* const* d_in, const int* in_sizes, int n_in,
                              void* d_out, int out_size, void* d_ws, size_t ws_size,
                              hipStream_t stream) {
  const float* latent = (const float*)d_in[0];
  const float* cb     = (const float*)d_in[1];
  float* out  = (float*)d_out;
  float* loss = out + (size_t)N_ * D_;             // element 8,388,608
  ushort* Xt  = (ushort*)out;                      // floats [0, 4194304)
  ushort* Ebf = (ushort*)(out + 4718592);          // floats [4718592, 4849664)
  float*  x2g = out + 4849664;                     // 32768 floats
  float*  e2  = out + 4882432;                     // 1024 floats
  unsigned long long* packed = (unsigned long long*)d_ws;

  hipMemsetAsync(packed, 0xFF, (size_t)N_ * 8, stream);
  hipMemsetAsync(loss, 0, sizeof(float), stream);
  hipLaunchKernelGGL(k_eprep,  dim3(64),   dim3(256), 0, stream, cb, Ebf, e2);
  hipLaunchKernelGGL(k_xprep,  dim3(1024), dim3(256), 0, stream, latent, Xt, x2g);
  hipLaunchKernelGGL(k_argmin, dim3(1024), dim3(256), 0, stream, Xt, Ebf, e2, x2g, packed);
  hipLaunchKernelGGL(k_out,    dim3(256),  dim3(256), 0, stream, latent, cb, packed, out, loss);
}